// Round 1
// baseline (540.812 us; speedup 1.0000x reference)
//
#include <hip/hip_runtime.h>

// LSTM fused kernel, fp32 VALU path (no fp32 MFMA on CDNA4).
// B=4096, T=512, I=10, H=32, O=1. Gate order (PyTorch): i, f, g, o.
//
// Decomposition:
//   wave (64 lanes) handles TWO batch elements end-to-end (ILP to hide the
//   per-step serial dependency). Lane t owns gate rows {t, t+64}:
//     t in [0,32):  rows t     = i-gate k=t,   rows t+64  = g-gate k=t
//     t in [32,64): rows t     = f-gate k=t-32, rows t+64 = o-gate k=t-32
//   Per-lane register-resident weights: W_ih 2x10 + W_hh 2x32 = 84 VGPRs,
//   loaded once, reused 512 steps (weights from LDS per-FMA would be
//   LDS-pipe-bound).
//   h lives in LDS (32 floats/batch): lanes 0..31 write h_k, all 64 lanes
//   broadcast-read it as float4 (wave-uniform address -> no bank conflicts,
//   no __syncthreads needed: DS ops within a wave are ordered).
//   f,o cross from upper lanes to lower lanes via __shfl.

#define T_SZ 512
#define I_SZ 10
#define H_SZ 32

__device__ __forceinline__ float sigmoid_fast(float v) {
    // 1/(1+e^-v); v_exp_f32 + v_rcp_f32, ~1-2 ulp, fine vs 6.6e-3 threshold
    return __builtin_amdgcn_rcpf(1.0f + __expf(-v));
}

__device__ __forceinline__ float tanh_fast(float v) {
    // tanh(x) = 2*sigmoid(2x) - 1
    return 2.0f * sigmoid_fast(2.0f * v) - 1.0f;
}

__global__ __launch_bounds__(256, 2)
void lstm_fused(const float* __restrict__ x,
                const float* __restrict__ W_ih,
                const float* __restrict__ W_hh,
                const float* __restrict__ b_ih,
                const float* __restrict__ b_hh,
                const float* __restrict__ W_dense,
                const float* __restrict__ b_dense,
                float* __restrict__ out)
{
    const int lane = threadIdx.x & 63;
    const int slot = threadIdx.x >> 6;          // wave within block (0..3)
    const int wid  = blockIdx.x * 4 + slot;     // global wave id (0..2047)
    const int bA   = wid * 2;
    const int bB   = bA + 1;

    const int j0 = lane;                        // gate row 0..63 (i | f)
    const int j1 = lane + 64;                   // gate row 64..127 (g | o)

    // ---- register-resident weights ----
    float wih0[I_SZ], wih1[I_SZ];
    #pragma unroll
    for (int i = 0; i < I_SZ; ++i) {
        wih0[i] = W_ih[j0 * I_SZ + i];
        wih1[i] = W_ih[j1 * I_SZ + i];
    }
    float whh0[H_SZ], whh1[H_SZ];
    #pragma unroll
    for (int k = 0; k < H_SZ; ++k) {
        whh0[k] = W_hh[j0 * H_SZ + k];
        whh1[k] = W_hh[j1 * H_SZ + k];
    }
    const float bias0 = b_ih[j0] + b_hh[j0];    // b_ih + b_hh folded once
    const float bias1 = b_ih[j1] + b_hh[j1];

    // ---- per-wave h state in LDS (two batches per wave) ----
    __shared__ float lds_h[4][2][H_SZ];
    if (lane < H_SZ) {
        lds_h[slot][0][lane] = 0.0f;
        lds_h[slot][1][lane] = 0.0f;
    }
    // wave-local DS ordering guarantees visibility; no barrier needed.

    const float* xA = x + (size_t)bA * (T_SZ * I_SZ);
    const float* xB = x + (size_t)bB * (T_SZ * I_SZ);

    float cA = 0.0f, cB = 0.0f;
    float hA = 0.0f, hB = 0.0f;

    // ---- software pipeline: in* = bias + W_ih . x_t for the current t ----
    float inA0, inA1, inB0, inB1;
    {
        float xcA[I_SZ], xcB[I_SZ];
        #pragma unroll
        for (int i = 0; i < I_SZ; i += 2) {     // rows are 8B-aligned
            float2 vA = *(const float2*)(xA + i);
            float2 vB = *(const float2*)(xB + i);
            xcA[i] = vA.x; xcA[i + 1] = vA.y;
            xcB[i] = vB.x; xcB[i + 1] = vB.y;
        }
        inA0 = bias0; inA1 = bias1; inB0 = bias0; inB1 = bias1;
        #pragma unroll
        for (int i = 0; i < I_SZ; ++i) {
            inA0 += wih0[i] * xcA[i];  inA1 += wih1[i] * xcA[i];
            inB0 += wih0[i] * xcB[i];  inB1 += wih1[i] * xcB[i];
        }
    }

    for (int t = 0; t < T_SZ; ++t) {
        const bool more = (t + 1 < T_SZ);

        // prefetch next step's x while this step computes
        float xnA[I_SZ], xnB[I_SZ];
        if (more) {
            const float* pA = xA + (t + 1) * I_SZ;
            const float* pB = xB + (t + 1) * I_SZ;
            #pragma unroll
            for (int i = 0; i < I_SZ; i += 2) {
                float2 vA = *(const float2*)(pA + i);
                float2 vB = *(const float2*)(pB + i);
                xnA[i] = vA.x; xnA[i + 1] = vA.y;
                xnB[i] = vB.x; xnB[i + 1] = vB.y;
            }
        }

        // ---- recurrent part: a += W_hh . h_prev  (h broadcast from LDS) ----
        float aA0 = inA0, aA1 = inA1, aB0 = inB0, aB1 = inB1;
        #pragma unroll
        for (int k = 0; k < H_SZ; k += 4) {
            float4 h4A = *(const float4*)&lds_h[slot][0][k];
            float4 h4B = *(const float4*)&lds_h[slot][1][k];
            aA0 += whh0[k+0] * h4A.x;  aA1 += whh1[k+0] * h4A.x;
            aB0 += whh0[k+0] * h4B.x;  aB1 += whh1[k+0] * h4B.x;
            aA0 += whh0[k+1] * h4A.y;  aA1 += whh1[k+1] * h4A.y;
            aB0 += whh0[k+1] * h4B.y;  aB1 += whh1[k+1] * h4B.y;
            aA0 += whh0[k+2] * h4A.z;  aA1 += whh1[k+2] * h4A.z;
            aB0 += whh0[k+2] * h4B.z;  aB1 += whh1[k+2] * h4B.z;
            aA0 += whh0[k+3] * h4A.w;  aA1 += whh1[k+3] * h4A.w;
            aB0 += whh0[k+3] * h4B.w;  aB1 += whh1[k+3] * h4B.w;
        }

        // ---- activations (branchless; lanes<32: {i, g=tanh}, lanes>=32: {f, o}) ----
        const bool lower = (lane < H_SZ);
        float actA0 = sigmoid_fast(aA0);            // i (lower) | f (upper)
        float actB0 = sigmoid_fast(aB0);
        float argA1 = lower ? 2.0f * aA1 : aA1;     // g needs tanh = 2*sig(2x)-1
        float argB1 = lower ? 2.0f * aB1 : aB1;
        float sA1 = sigmoid_fast(argA1);
        float sB1 = sigmoid_fast(argB1);
        float actA1 = lower ? 2.0f * sA1 - 1.0f : sA1;  // g (lower) | o (upper)
        float actB1 = lower ? 2.0f * sB1 - 1.0f : sB1;

        // pull f,o from partner lane (lane|32); upper lanes get own value (unused)
        float fA = __shfl(actA0, lane | 32);
        float oA = __shfl(actA1, lane | 32);
        float fB = __shfl(actB0, lane | 32);
        float oB = __shfl(actB1, lane | 32);

        cA = fA * cA + actA0 * actA1;   // f*c + i*g  (valid on lanes<32)
        cB = fB * cB + actB0 * actB1;
        hA = oA * tanh_fast(cA);
        hB = oB * tanh_fast(cB);

        if (lower) {
            lds_h[slot][0][lane] = hA;
            lds_h[slot][1][lane] = hB;
        }

        // ---- input-gate part for next step (independent of h chain) ----
        if (more) {
            inA0 = bias0; inA1 = bias1; inB0 = bias0; inB1 = bias1;
            #pragma unroll
            for (int i = 0; i < I_SZ; ++i) {
                inA0 += wih0[i] * xnA[i];  inA1 += wih1[i] * xnA[i];
                inB0 += wih0[i] * xnB[i];  inB1 += wih1[i] * xnB[i];
            }
        }
    }

    // ---- dense head: out[b] = h_last . W_dense[0,:] + b_dense[0] ----
    float wd = (lane < H_SZ) ? W_dense[lane] : 0.0f;
    float vA = (lane < H_SZ) ? hA * wd : 0.0f;
    float vB = (lane < H_SZ) ? hB * wd : 0.0f;
    #pragma unroll
    for (int m = 16; m >= 1; m >>= 1) {
        vA += __shfl_xor(vA, m);
        vB += __shfl_xor(vB, m);
    }
    if (lane == 0) {
        const float bd = b_dense[0];
        out[bA] = vA + bd;
        out[bB] = vB + bd;
    }
}

extern "C" void kernel_launch(void* const* d_in, const int* in_sizes, int n_in,
                              void* d_out, int out_size, void* d_ws, size_t ws_size,
                              hipStream_t stream) {
    const float* x       = (const float*)d_in[0];
    const float* W_ih    = (const float*)d_in[1];
    const float* W_hh    = (const float*)d_in[2];
    const float* b_ih    = (const float*)d_in[3];
    const float* b_hh    = (const float*)d_in[4];
    const float* W_dense = (const float*)d_in[5];
    const float* b_dense = (const float*)d_in[6];
    float* out = (float*)d_out;

    // 512 blocks x 256 threads = 2048 waves x 2 batches/wave = 4096 batches
    lstm_fused<<<dim3(512), dim3(256), 0, stream>>>(
        x, W_ih, W_hh, b_ih, b_hh, W_dense, b_dense, out);
}

// Round 2
// 495.609 us; speedup vs baseline: 1.0912x; 1.0912x over previous
//
#include <hip/hip_runtime.h>

// LSTM fused, fp32 packed-VALU path (no fp32 MFMA on CDNA4; peak 157 TF is
// v_pk_fma_f32). B=4096, T=512, I=10, H=32, O=1. Gates: i, f, g, o.
//
// Round-2 structure:
//   ONE batch per wave, 4096 waves total = 4 waves/SIMD, __launch_bounds__(256,4)
//   => 128-VGPR cap so all weights live in arch VGPRs (R1's 72-VGPR report +
//   2.3x VALU overhead = allocator pushed weights to AGPRs and paid
//   v_accvgpr_read/write around every FMA).
//   Lane L owns gate rows {L, L+64}:
//     L<32:  row L = i_L,    row L+64 = g_L
//     L>=32: row L = f_(L-32), row L+64 = o_(L-32)
//   Weights per lane packed as float2 over the k-dimension:
//     whh: 16+16 v2f (64 VGPR), wih: 5+5 v2f (20 VGPR) -- loaded once,
//     reused 512 steps. Dot products via v_pk_fma_f32 (half the instrs),
//     one horizontal add per gate per step.
//   h (32 floats) in per-wave LDS; all lanes broadcast-read it as float4
//   (wave-uniform address = free broadcast; R1 showed this is not the
//   binding pipe). No barriers ever: DS ops are wave-ordered and each wave
//   only touches its own slot. Upper lanes write junk h to their own LDS
//   slots (never read).
//   f,o cross upper->lower lanes via 2 ds_bpermute (__shfl lane^32).

#define T_SZ 512
#define I_SZ 10
#define H_SZ 32

typedef float v2f __attribute__((ext_vector_type(2)));

__device__ __forceinline__ float sigmoid_fast(float v) {
    // 1/(1+e^-v): v_mul+v_exp+v_add+v_rcp. Same math as R1 (absmax 0.0).
    return __builtin_amdgcn_rcpf(1.0f + __expf(-v));
}

__device__ __forceinline__ float tanh_fast(float v) {
    return 2.0f * sigmoid_fast(2.0f * v) - 1.0f;
}

__device__ __forceinline__ v2f pkfma(v2f a, v2f b, v2f c) {
    // lowers to v_pk_fma_f32 on gfx90a+
    return __builtin_elementwise_fma(a, b, c);
}

__global__ __launch_bounds__(256, 4)
void lstm_fused(const float* __restrict__ x,
                const float* __restrict__ W_ih,
                const float* __restrict__ W_hh,
                const float* __restrict__ b_ih,
                const float* __restrict__ b_hh,
                const float* __restrict__ W_dense,
                const float* __restrict__ b_dense,
                float* __restrict__ out)
{
    const int lane = threadIdx.x & 63;
    const int slot = threadIdx.x >> 6;          // wave within block (0..3)
    const int b    = blockIdx.x * 4 + slot;     // batch index (0..4095)

    const int j0 = lane;                        // gate row: i (L<32) | f
    const int j1 = lane + 64;                   // gate row: g (L<32) | o

    // ---- register-resident weights, packed over k ----
    v2f wih0p[I_SZ / 2], wih1p[I_SZ / 2];
    #pragma unroll
    for (int i = 0; i < I_SZ / 2; ++i) {        // rows are 8B-aligned (40B pitch)
        float2 a = *(const float2*)(W_ih + j0 * I_SZ + 2 * i);
        float2 c = *(const float2*)(W_ih + j1 * I_SZ + 2 * i);
        wih0p[i] = (v2f){a.x, a.y};
        wih1p[i] = (v2f){c.x, c.y};
    }
    v2f whh0p[H_SZ / 2], whh1p[H_SZ / 2];
    #pragma unroll
    for (int k = 0; k < H_SZ / 2; ++k) {        // rows are 128B-aligned
        float2 a = *(const float2*)(W_hh + j0 * H_SZ + 2 * k);
        float2 c = *(const float2*)(W_hh + j1 * H_SZ + 2 * k);
        whh0p[k] = (v2f){a.x, a.y};
        whh1p[k] = (v2f){c.x, c.y};
    }
    const float bias0 = b_ih[j0] + b_hh[j0];
    const float bias1 = b_ih[j1] + b_hh[j1];

    // ---- per-wave h state in LDS (64 floats; upper 32 are junk-sink) ----
    __shared__ float lds_h[4][64];
    lds_h[slot][lane] = 0.0f;                   // unconditional, wave-ordered

    const float* __restrict__ xp = x + (size_t)b * (T_SZ * I_SZ);

    float c_st = 0.0f, h_st = 0.0f;
    const bool lower = (lane < H_SZ);
    const int  part  = lane ^ 32;               // partner lane for f,o pull

    // prefetch x_0
    v2f xn[I_SZ / 2];
    #pragma unroll
    for (int i = 0; i < I_SZ / 2; ++i) {
        float2 v = *(const float2*)(xp + 2 * i);
        xn[i] = (v2f){v.x, v.y};
    }
    xp += I_SZ;

    #pragma unroll 1
    for (int t = 0; t < T_SZ; ++t) {
        // ---- gate pre-activations: a = bias + W_ih.x_t + W_hh.h_{t-1} ----
        v2f a0 = (v2f){bias0, 0.0f};
        v2f a1 = (v2f){bias1, 0.0f};
        #pragma unroll
        for (int i = 0; i < I_SZ / 2; ++i) {
            a0 = pkfma(wih0p[i], xn[i], a0);
            a1 = pkfma(wih1p[i], xn[i], a1);
        }

        // prefetch next x while the h-part computes (WAR on xn is safe:
        // consuming FMAs issue before the loads in program order)
        if (t != T_SZ - 1) {
            #pragma unroll
            for (int i = 0; i < I_SZ / 2; ++i) {
                float2 v = *(const float2*)(xp + 2 * i);
                xn[i] = (v2f){v.x, v.y};
            }
            xp += I_SZ;
        }

        #pragma unroll
        for (int k = 0; k < H_SZ / 4; ++k) {    // 8x ds_read_b128, broadcast
            float4 h4 = *(const float4*)&lds_h[slot][4 * k];
            v2f hlo = (v2f){h4.x, h4.y};
            v2f hhi = (v2f){h4.z, h4.w};
            a0 = pkfma(whh0p[2 * k], hlo, a0);
            a1 = pkfma(whh1p[2 * k], hlo, a1);
            a0 = pkfma(whh0p[2 * k + 1], hhi, a0);
            a1 = pkfma(whh1p[2 * k + 1], hhi, a1);
        }
        const float g0 = a0.x + a0.y;           // row j0 pre-act (i | f)
        const float g1 = a1.x + a1.y;           // row j1 pre-act (g | o)

        // ---- activations (branchless; L<32: {i, g=tanh}, L>=32: {f, o}) ----
        float act0 = sigmoid_fast(g0);          // i | f
        float arg1 = lower ? 2.0f * g1 : g1;    // g needs tanh = 2*sig(2x)-1
        float s1   = sigmoid_fast(arg1);
        float act1 = lower ? 2.0f * s1 - 1.0f : s1;  // g | o

        // pull f,o from partner lane (lane^32); upper lanes get junk (unused)
        float f_g = __shfl(act0, part);
        float o_g = __shfl(act1, part);

        c_st = f_g * c_st + act0 * act1;        // f*c + i*g (valid on L<32)
        h_st = o_g * tanh_fast(c_st);

        lds_h[slot][lane] = h_st;               // upper lanes write junk-sink
    }

    // ---- dense head: out[b] = h_last . W_dense[0,:] + b_dense[0] ----
    float wd = lower ? W_dense[lane] : 0.0f;
    float v  = lower ? h_st * wd : 0.0f;
    #pragma unroll
    for (int m = 16; m >= 1; m >>= 1)
        v += __shfl_xor(v, m);                  // sums within each 32-group
    if (lane == 0)
        out[b] = v + b_dense[0];
}

extern "C" void kernel_launch(void* const* d_in, const int* in_sizes, int n_in,
                              void* d_out, int out_size, void* d_ws, size_t ws_size,
                              hipStream_t stream) {
    const float* x       = (const float*)d_in[0];
    const float* W_ih    = (const float*)d_in[1];
    const float* W_hh    = (const float*)d_in[2];
    const float* b_ih    = (const float*)d_in[3];
    const float* b_hh    = (const float*)d_in[4];
    const float* W_dense = (const float*)d_in[5];
    const float* b_dense = (const float*)d_in[6];
    float* out = (float*)d_out;

    // 1024 blocks x 256 threads = 4096 waves x 1 batch/wave
    lstm_fused<<<dim3(1024), dim3(256), 0, stream>>>(
        x, W_ih, W_hh, b_ih, b_hh, W_dense, b_dense, out);
}

// Round 3
// 422.475 us; speedup vs baseline: 1.2801x; 1.1731x over previous
//
#include <hip/hip_runtime.h>

// LSTM via split-bf16 MFMA. B=4096, T=512, I=10, H=32, O=1. Gates i,f,g,o.
//
// R1/R2 were LDS-pipe-bound (~1800 DS-cyc/CU/step broadcasting h per batch).
// Fix: MFMA processes 16 batches per wave so the cross-lane h sharing happens
// inside the matrix unit, not the DS pipe.
//
// Block = 4 waves = 16 batches (one group). Wave w owns hidden slice
// J = [8w, 8w+8) as 2 N-tiles of mfma_f32_16x16x32_bf16:
//   tile0 cols: c<8 -> i_{8w+c}, c>=8 -> f_{8w+c-8}
//   tile1 cols: c<8 -> g_{8w+c}, c>=8 -> o_{8w+c-8}
// C layout (HW-verified): col=lane&15, row=quad*4+reg = batch.
// A layout (HW-verified): A[m=lane&15][k=quad*8+j]  (m=batch, k=hidden/input)
// B layout (inferred mirror): B[k=quad*8+j][n=lane&15]
//
// fp32 accuracy without fp32 MFMA: truncation split W=Whi+Wlo, h=hhi+hlo,
// 3 MFMAs per operand pair (Whi*hhi + Whi*hlo + Wlo*hhi), fp32 C. Residual
// ~2^-16 relative.
//
// Per step: 12 MFMAs, 4 ds_write_b32 + 2 ds_read_b128 (h ping-pong exchange),
// 1 barrier. f,o cross col+8 -> col via DPP row_ror:8 (VALU pipe, not DS).
// Bias folds into MFMA C-init. x prefetched one step ahead; x-chain MFMAs
// overlap the h ds_read latency.

#define T_SZ 512
#define I_SZ 10
#define H_SZ 32

typedef short bf16x8 __attribute__((ext_vector_type(8)));
typedef float f32x4  __attribute__((ext_vector_type(4)));
typedef int   i32x4  __attribute__((ext_vector_type(4)));

union FB { i32x4 i; bf16x8 b; };

static __device__ __forceinline__ bf16x8 fragi(const int d[4]) {
    FB u; u.i = (i32x4){d[0], d[1], d[2], d[3]}; return u.b;
}

// packed-pair perm: low16 = top16(e), high16 = top16(o)
static __device__ __forceinline__ int pack_hi16(float o, float e) {
    return (int)__builtin_amdgcn_perm(__float_as_uint(o), __float_as_uint(e), 0x07060302u);
}

// truncation split of 8 fp32 -> bf16-hi frag + bf16-lo frag (hi+lo ~= fp32)
static __device__ __forceinline__ void split8(const float w[8], int hi[4], int lo[4]) {
    #pragma unroll
    for (int j = 0; j < 4; ++j) {
        float e = w[2*j], o = w[2*j+1];
        float eh = __uint_as_float(__float_as_uint(e) & 0xFFFF0000u);
        float oh = __uint_as_float(__float_as_uint(o) & 0xFFFF0000u);
        hi[j] = pack_hi16(o, e);
        lo[j] = pack_hi16(o - oh, e - eh);
    }
}

static __device__ __forceinline__ float dpp_ror8(float v) {
    // within each 16-lane DPP row: lane c gets lane (c+8)&15 -> partner column
    return __int_as_float(__builtin_amdgcn_mov_dpp(__float_as_int(v), 0x128, 0xF, 0xF, true));
}

static __device__ __forceinline__ float sigm_from_exp(float e) { // sigma given e=exp(-x)
    return __builtin_amdgcn_rcpf(1.0f + e);
}

__global__ __launch_bounds__(256, 1)
void lstm_mfma(const float* __restrict__ x, const float* __restrict__ W_ih,
               const float* __restrict__ W_hh, const float* __restrict__ b_ih,
               const float* __restrict__ b_hh, const float* __restrict__ W_dense,
               const float* __restrict__ b_dense, float* __restrict__ out)
{
    const int tid   = threadIdx.x;
    const int wv    = tid >> 6;          // wave 0..3 = hidden slice
    const int lane  = tid & 63;
    const int col   = lane & 15;         // N-col in tile / batch row for A
    const int quad  = lane >> 4;
    const int bbase = blockIdx.x * 16;   // 256 blocks x 16 batches

    const int  jloc = col & 7;
    const int  hid  = 8 * wv + jloc;     // hidden index of this column
    const bool isA  = (col < 8);         // i/g columns (these lanes own c,h)
    const int  row0 = (isA ? 0 : 32) + hid;   // W row: i | f
    const int  row1 = (isA ? 64 : 96) + hid;  // W row: g | o

    // ---- B fragments, built once, register-resident ----
    int bhh0h[4], bhh0l[4], bhh1h[4], bhh1l[4];
    {
        float w[8];
        const float* p = W_hh + row0 * H_SZ + 8 * quad;
        #pragma unroll
        for (int j = 0; j < 4; ++j) { float2 v = *(const float2*)(p + 2*j); w[2*j] = v.x; w[2*j+1] = v.y; }
        split8(w, bhh0h, bhh0l);
        p = W_hh + row1 * H_SZ + 8 * quad;
        #pragma unroll
        for (int j = 0; j < 4; ++j) { float2 v = *(const float2*)(p + 2*j); w[2*j] = v.x; w[2*j+1] = v.y; }
        split8(w, bhh1h, bhh1l);
    }
    int bih0h[4], bih0l[4], bih1h[4], bih1l[4];
    {
        float w[8];
        #pragma unroll
        for (int j = 0; j < 8; ++j) w[j] = 0.0f;
        if (quad == 0) {
            const float* p = W_ih + row0 * I_SZ;
            #pragma unroll
            for (int j = 0; j < 4; ++j) { float2 v = *(const float2*)(p + 2*j); w[2*j] = v.x; w[2*j+1] = v.y; }
        } else if (quad == 1) {
            float2 v = *(const float2*)(W_ih + row0 * I_SZ + 8); w[0] = v.x; w[1] = v.y;
        }
        split8(w, bih0h, bih0l);
        #pragma unroll
        for (int j = 0; j < 8; ++j) w[j] = 0.0f;
        if (quad == 0) {
            const float* p = W_ih + row1 * I_SZ;
            #pragma unroll
            for (int j = 0; j < 4; ++j) { float2 v = *(const float2*)(p + 2*j); w[2*j] = v.x; w[2*j+1] = v.y; }
        } else if (quad == 1) {
            float2 v = *(const float2*)(W_ih + row1 * I_SZ + 8); w[0] = v.x; w[1] = v.y;
        }
        split8(w, bih1h, bih1l);
    }

    const float bias0  = b_ih[row0] + b_hh[row0];
    const float bias1  = b_ih[row1] + b_hh[row1];
    const f32x4 biasv0 = {bias0, bias0, bias0, bias0};
    const f32x4 biasv1 = {bias1, bias1, bias1, bias1};
    const f32x4 zerov  = {0.f, 0.f, 0.f, 0.f};

    // ping-pong packed h: dword = (hi-bf16 | lo-bf16<<16), row stride 36 dwords
    // (16B-aligned lane reads; write banks 2-way max, read 4-way on 2 instrs)
    __shared__ int lds_h[2][16 * 36];
    for (int i = tid; i < 16 * 36; i += 256) lds_h[0][i] = 0;
    __syncthreads();

    // ---- x prefetch (A-operand role: m=col=batch, k=quad*8+j) ----
    const int mb = col;
    const float* xrow = x + ((size_t)(bbase + mb) * T_SZ) * I_SZ;
    float xc[8];
    #pragma unroll
    for (int j = 0; j < 8; ++j) xc[j] = 0.0f;
    if (quad == 0) {
        #pragma unroll
        for (int j = 0; j < 4; ++j) { float2 v = *(const float2*)(xrow + 2*j); xc[2*j] = v.x; xc[2*j+1] = v.y; }
    } else if (quad == 1) {
        float2 v = *(const float2*)(xrow + 8); xc[0] = v.x; xc[1] = v.y;
    }

    f32x4 c4 = {0.f, 0.f, 0.f, 0.f};
    const float m1 = isA ? -2.0f : -1.0f;   // tanh via 2*sigma(2x)-1 on g-cols

    #pragma unroll 2
    for (int t = 0; t < T_SZ; ++t) {
        const int rb = t & 1;

        // issue h reads early (consumed after the x-chain)
        const int* hp = &lds_h[rb][mb * 36 + 8 * quad];
        i32x4 h03 = *(const i32x4*)(hp);
        i32x4 h47 = *(const i32x4*)(hp + 4);

        // x-chain (independent of h) overlaps LDS latency; bias in C-init
        int xh[4], xl[4];
        split8(xc, xh, xl);
        f32x4 ax0 = __builtin_amdgcn_mfma_f32_16x16x32_bf16(fragi(xh), fragi(bih0h), biasv0, 0, 0, 0);
        ax0 = __builtin_amdgcn_mfma_f32_16x16x32_bf16(fragi(xl), fragi(bih0h), ax0, 0, 0, 0);
        ax0 = __builtin_amdgcn_mfma_f32_16x16x32_bf16(fragi(xh), fragi(bih0l), ax0, 0, 0, 0);
        f32x4 ax1 = __builtin_amdgcn_mfma_f32_16x16x32_bf16(fragi(xh), fragi(bih1h), biasv1, 0, 0, 0);
        ax1 = __builtin_amdgcn_mfma_f32_16x16x32_bf16(fragi(xl), fragi(bih1h), ax1, 0, 0, 0);
        ax1 = __builtin_amdgcn_mfma_f32_16x16x32_bf16(fragi(xh), fragi(bih1l), ax1, 0, 0, 0);

        // prefetch next x (fills xc for next iteration)
        if (t + 1 < T_SZ) {
            const float* xr = xrow + (t + 1) * I_SZ;
            if (quad == 0) {
                #pragma unroll
                for (int j = 0; j < 4; ++j) { float2 v = *(const float2*)(xr + 2*j); xc[2*j] = v.x; xc[2*j+1] = v.y; }
            } else if (quad == 1) {
                float2 v = *(const float2*)(xr + 8); xc[0] = v.x; xc[1] = v.y;
            }
        }

        // h A-frags: unpack (hi|lo) dwords into bf16-pair frags
        int ah[4], al[4];
        ah[0] = (int)__builtin_amdgcn_perm((unsigned)h03.y, (unsigned)h03.x, 0x05040100u);
        ah[1] = (int)__builtin_amdgcn_perm((unsigned)h03.w, (unsigned)h03.z, 0x05040100u);
        ah[2] = (int)__builtin_amdgcn_perm((unsigned)h47.y, (unsigned)h47.x, 0x05040100u);
        ah[3] = (int)__builtin_amdgcn_perm((unsigned)h47.w, (unsigned)h47.z, 0x05040100u);
        al[0] = (int)__builtin_amdgcn_perm((unsigned)h03.y, (unsigned)h03.x, 0x07060302u);
        al[1] = (int)__builtin_amdgcn_perm((unsigned)h03.w, (unsigned)h03.z, 0x07060302u);
        al[2] = (int)__builtin_amdgcn_perm((unsigned)h47.y, (unsigned)h47.x, 0x07060302u);
        al[3] = (int)__builtin_amdgcn_perm((unsigned)h47.w, (unsigned)h47.z, 0x07060302u);
        f32x4 ahh0 = __builtin_amdgcn_mfma_f32_16x16x32_bf16(fragi(ah), fragi(bhh0h), zerov, 0, 0, 0);
        ahh0 = __builtin_amdgcn_mfma_f32_16x16x32_bf16(fragi(al), fragi(bhh0h), ahh0, 0, 0, 0);
        ahh0 = __builtin_amdgcn_mfma_f32_16x16x32_bf16(fragi(ah), fragi(bhh0l), ahh0, 0, 0, 0);
        f32x4 ahh1 = __builtin_amdgcn_mfma_f32_16x16x32_bf16(fragi(ah), fragi(bhh1h), zerov, 0, 0, 0);
        ahh1 = __builtin_amdgcn_mfma_f32_16x16x32_bf16(fragi(al), fragi(bhh1h), ahh1, 0, 0, 0);
        ahh1 = __builtin_amdgcn_mfma_f32_16x16x32_bf16(fragi(ah), fragi(bhh1l), ahh1, 0, 0, 0);

        // activations, state update, h write (batch = 4*quad + r)
        #pragma unroll
        for (int r = 0; r < 4; ++r) {
            float p0 = ax0[r] + ahh0[r];            // i | f preact
            float p1 = ax1[r] + ahh1[r];            // g | o preact
            float s0 = sigm_from_exp(__expf(-p0));  // i | f
            float rr = sigm_from_exp(__expf(m1 * p1));
            float s1 = isA ? 2.0f * rr - 1.0f : rr; // g | o
            float fg = dpp_ror8(s0);                // f (valid on isA lanes)
            float og = dpp_ror8(s1);                // o
            float cn = fg * c4[r] + s0 * s1;
            c4[r] = cn;
            float th = 2.0f * sigm_from_exp(__expf(-2.0f * cn)) - 1.0f;
            float h  = og * th;
            unsigned hb  = __float_as_uint(h);
            float    hif = __uint_as_float(hb & 0xFFFF0000u);
            int packed = (int)__builtin_amdgcn_perm(__float_as_uint(h - hif), hb, 0x07060302u);
            if (isA)
                lds_h[rb ^ 1][(4 * quad + r) * 36 + hid] = packed;
        }
        __syncthreads();
    }

    // ---- dense head: final h sits in buffer (T_SZ & 1) = 0 ----
    if (wv == 0 && lane < 16) {
        float acc = b_dense[0];
        #pragma unroll 4
        for (int j = 0; j < H_SZ; ++j) {
            unsigned d = (unsigned)lds_h[0][lane * 36 + j];
            float hv = __uint_as_float(d << 16) + __uint_as_float(d & 0xFFFF0000u);
            acc += hv * W_dense[j];
        }
        out[bbase + lane] = acc;
    }
}

extern "C" void kernel_launch(void* const* d_in, const int* in_sizes, int n_in,
                              void* d_out, int out_size, void* d_ws, size_t ws_size,
                              hipStream_t stream) {
    const float* x       = (const float*)d_in[0];
    const float* W_ih    = (const float*)d_in[1];
    const float* W_hh    = (const float*)d_in[2];
    const float* b_ih    = (const float*)d_in[3];
    const float* b_hh    = (const float*)d_in[4];
    const float* W_dense = (const float*)d_in[5];
    const float* b_dense = (const float*)d_in[6];
    float* out = (float*)d_out;

    // 256 blocks x 256 threads: 1 group of 16 batches per block
    lstm_mfma<<<dim3(256), dim3(256), 0, stream>>>(
        x, W_ih, W_hh, b_ih, b_hh, W_dense, b_dense, out);
}